// Round 3
// baseline (1529.751 us; speedup 1.0000x reference)
//
#include <hip/hip_runtime.h>
#include <hip/hip_bf16.h>

// Problem constants (match reference)
#define NN 100000
#define NG 512
#define H  128

typedef _Float16 half8  __attribute__((ext_vector_type(8)));
typedef _Float16 half4v __attribute__((ext_vector_type(4)));
typedef _Float16 half2v __attribute__((ext_vector_type(2)));
typedef float f32x4 __attribute__((ext_vector_type(4)));

// ---------------------------------------------------------------------------
// Merged: blocks [0,128) transpose+fp16-convert W1/W2; blocks [128,..) dst hist
__global__ __launch_bounds__(256) void k_wprep_hist(const float* __restrict__ W1,
                                                    const float* __restrict__ W2,
                                                    _Float16* __restrict__ Wt1,
                                                    _Float16* __restrict__ Wt2,
                                                    const int* __restrict__ dst,
                                                    int* __restrict__ deg, int E) {
    int bb = blockIdx.x;
    if (bb < 128) {
        const float* W = (bb < 64) ? W1 : W2;
        _Float16* Wt = (bb < 64) ? Wt1 : Wt2;
        int i = (bb & 63) * 256 + threadIdx.x;    // 0..16383
        int k = i >> 7, n = i & 127;
        Wt[n * 128 + k] = (_Float16)W[i];
        return;
    }
    int e = (bb - 128) * 256 + threadIdx.x;
    if (e < E) atomicAdd(&deg[dst[e]], 1);
}

// per-block exclusive scan (256 elems), partial sums to bsum
__global__ __launch_bounds__(256) void k_scan_block(const int* __restrict__ deg,
                                                    int* __restrict__ rowptr,
                                                    int* __restrict__ bsum, int n) {
    __shared__ int s[256];
    int tid = threadIdx.x;
    int i = blockIdx.x * 256 + tid;
    int v = (i < n) ? deg[i] : 0;
    s[tid] = v;
    __syncthreads();
    #pragma unroll
    for (int off = 1; off < 256; off <<= 1) {
        int t = (tid >= off) ? s[tid - off] : 0;
        __syncthreads();
        s[tid] += t;
        __syncthreads();
    }
    if (i < n) rowptr[i] = s[tid] - v;            // exclusive within block
    if (tid == 255) bsum[blockIdx.x] = s[255];    // block total
}

// scan of block sums (nb <= 512), single block
__global__ __launch_bounds__(512) void k_scan_top(int* __restrict__ bsum, int nb) {
    __shared__ int s[512];
    int tid = threadIdx.x;
    int v = (tid < nb) ? bsum[tid] : 0;
    s[tid] = v;
    __syncthreads();
    #pragma unroll
    for (int off = 1; off < 512; off <<= 1) {
        int t = (tid >= off) ? s[tid - off] : 0;
        __syncthreads();
        s[tid] += t;
        __syncthreads();
    }
    if (tid < nb) bsum[tid] = s[tid] - v;         // exclusive
}

// finalize: rowptr += block offset; cursor = rowptr; dinv = rsqrt(deg+1)
__global__ __launch_bounds__(256) void k_scan_fin(int* __restrict__ rowptr,
                                                  const int* __restrict__ bsum,
                                                  const int* __restrict__ deg,
                                                  int* __restrict__ cursor,
                                                  float* __restrict__ dinv,
                                                  int n, int E) {
    int i = blockIdx.x * 256 + threadIdx.x;
    if (i >= n) return;
    int r = rowptr[i] + bsum[i >> 8];
    rowptr[i] = r;
    cursor[i] = r;
    dinv[i] = rsqrtf((float)deg[i] + 1.0f);       // +1 self-loop; always > 0
    if (i == 0) rowptr[n] = E;
}

// ---------------------------------------------------------------------------
// Fused: blocks [0,nfb) fill CSR col; blocks [nfb,..) do GEMM1
// (tS = (x@W1)*dinv[row], fp16 out). LDS-free MFMA GEMM.
__global__ __launch_bounds__(256) void k_fill_gemm1(
        const int* __restrict__ src, const int* __restrict__ dst,
        int* __restrict__ cursor, int* __restrict__ col, int E, int nfb,
        const float* __restrict__ x, const _Float16* __restrict__ Wt1,
        const float* __restrict__ dinv, _Float16* __restrict__ tS, int n) {
    if ((int)blockIdx.x < nfb) {
        int e = blockIdx.x * 256 + threadIdx.x;
        if (e >= E) return;
        int d = dst[e];
        int pos = atomicAdd(&cursor[d], 1);
        col[pos] = src[e];
        return;
    }
    const int row0 = ((int)blockIdx.x - nfb) * 64;
    const int tid = threadIdx.x;
    const int w = tid >> 6, lane = tid & 63;
    const int l16 = lane & 15, quad = lane >> 4;
    const int Arow = row0 + w * 16 + l16;
    f32x4 acc[8] = {};
    #pragma unroll
    for (int kk = 0; kk < 4; ++kk) {
        half8 af;
        if (Arow < n) {
            const float* ap = x + (size_t)Arow * H + kk * 32 + quad * 8;
            float4 a0 = ((const float4*)ap)[0];
            float4 a1 = ((const float4*)ap)[1];
            af[0] = (_Float16)a0.x; af[1] = (_Float16)a0.y;
            af[2] = (_Float16)a0.z; af[3] = (_Float16)a0.w;
            af[4] = (_Float16)a1.x; af[5] = (_Float16)a1.y;
            af[6] = (_Float16)a1.z; af[7] = (_Float16)a1.w;
        } else {
            #pragma unroll
            for (int j = 0; j < 8; ++j) af[j] = (_Float16)0.0f;
        }
        #pragma unroll
        for (int nt = 0; nt < 8; ++nt) {
            half8 bf = *((const half8*)(Wt1 + (nt * 16 + l16) * H + kk * 32 + quad * 8));
            acc[nt] = __builtin_amdgcn_mfma_f32_16x16x32_f16(af, bf, acc[nt], 0, 0, 0);
        }
    }
    #pragma unroll
    for (int r = 0; r < 4; ++r) {
        int R = row0 + w * 16 + quad * 4 + r;
        if (R < n) {
            float sc = dinv[R];
            _Float16* crow = tS + (size_t)R * H + l16;
            #pragma unroll
            for (int nt = 0; nt < 8; ++nt)
                crow[nt * 16] = (_Float16)(acc[nt][r] * sc);
        }
    }
}

// ---------------------------------------------------------------------------
// GEMM2, LDS-free: tS2 = (h1 @ W2) * dinv[row]
__global__ __launch_bounds__(256) void k_gemm2(const _Float16* __restrict__ h1,
                                               const _Float16* __restrict__ Wt2,
                                               const float* __restrict__ dinv,
                                               _Float16* __restrict__ tS2, int n) {
    const int row0 = blockIdx.x * 64;
    const int tid = threadIdx.x;
    const int w = tid >> 6, lane = tid & 63;
    const int l16 = lane & 15, quad = lane >> 4;
    const int Arow = row0 + w * 16 + l16;
    f32x4 acc[8] = {};
    #pragma unroll
    for (int kk = 0; kk < 4; ++kk) {
        half8 af;
        if (Arow < n) {
            af = ((const half8*)(h1 + (size_t)Arow * H))[kk * 4 + quad];
        } else {
            #pragma unroll
            for (int j = 0; j < 8; ++j) af[j] = (_Float16)0.0f;
        }
        #pragma unroll
        for (int nt = 0; nt < 8; ++nt) {
            half8 bf = *((const half8*)(Wt2 + (nt * 16 + l16) * H + kk * 32 + quad * 8));
            acc[nt] = __builtin_amdgcn_mfma_f32_16x16x32_f16(af, bf, acc[nt], 0, 0, 0);
        }
    }
    #pragma unroll
    for (int r = 0; r < 4; ++r) {
        int R = row0 + w * 16 + quad * 4 + r;
        if (R < n) {
            float sc = dinv[R];
            _Float16* crow = tS2 + (size_t)R * H + l16;
            #pragma unroll
            for (int nt = 0; nt < 8; ++nt)
                crow[nt * 16] = (_Float16)(acc[nt][r] * sc);
        }
    }
}

// ---------------------------------------------------------------------------
// Fragment loaders: F halves (F*2 bytes) per lane. NOL1 variant bypasses L1
// via agent-scope relaxed atomic loads (gather2 only — no store stream there).
template <int F, bool NOL1>
__device__ __forceinline__ void frag_load(const char* p, float* t) {
    if constexpr (F == 4) {
        union { unsigned long long u; half4v h; } c;
        if constexpr (NOL1) {
            c.u = __hip_atomic_load((const unsigned long long*)p,
                                    __ATOMIC_RELAXED, __HIP_MEMORY_SCOPE_AGENT);
        } else {
            c.h = *(const half4v*)p;
        }
        t[0] = (float)c.h[0]; t[1] = (float)c.h[1];
        t[2] = (float)c.h[2]; t[3] = (float)c.h[3];
    } else {
        union { unsigned int u; half2v h; } c;
        if constexpr (NOL1) {
            c.u = __hip_atomic_load((const unsigned int*)p,
                                    __ATOMIC_RELAXED, __HIP_MEMORY_SCOPE_AGENT);
        } else {
            c.h = *(const half2v*)p;
        }
        t[0] = (float)c.h[0]; t[1] = (float)c.h[1];
    }
}

// ---------------------------------------------------------------------------
// Gather core over a FEATURE SLICE of each row. Row stride stays 256B; a pass
// touches only bytes [hoffB, hoffB + 16*F*2) of each row, so the L2 footprint
// is 25.6MB * (F/8): F=4 -> 12.8MB (halves), F=2 -> 6.4MB (quarters).
// Per-XCD L2 is 4MiB; smaller footprint => higher hit rate => fewer of the
// ~900-cycle L2-miss round trips that are the measured wall (r0-r2 analysis).
// 16-lane fragments still cover whole 128B cache lines (F=4 exactly one).
// Inner pattern = proven round-0 core (2 loads in flight, unmasked groups).
template <int F, bool NOL1>
__device__ __forceinline__ void gather_rows_f(const _Float16* __restrict__ tS,
                                              const int* __restrict__ col,
                                              int node, int e0, int end, int hoffB,
                                              float acc[F]) {
    const int lane = threadIdx.x & 63;
    const int q = lane >> 4;
    const int l16 = lane & 15;
    const char* tSb = (const char*)tS;       // rows are 256B; 32-bit byte offsets
    const uint32_t fo = (uint32_t)(hoffB + l16 * (F * 2));
    float a0[F] = {}, a1[F] = {};
    if (q == 0) {                            // self-loop row (cached load)
        float t[F];
        frag_load<F, false>(tSb + (((uint32_t)node << 8) + fo), t);
        #pragma unroll
        for (int i = 0; i < F; ++i) a0[i] = t[i];
    }
    for (int base = e0; base < end; base += 64) {
        int ce = base + lane;
        int cidx = (ce < end) ? col[ce] : 0;
        int m = min(64, end - base);
        int nf = m >> 2;                     // full groups of 4 edges
        int g = 0;
        for (; g + 2 <= nf; g += 2) {
            int s0 = __shfl(cidx, 4 * g + q);
            int s1 = __shfl(cidx, 4 * g + 4 + q);
            float t0[F], t1[F];
            frag_load<F, NOL1>(tSb + (((uint32_t)s0 << 8) + fo), t0);
            frag_load<F, NOL1>(tSb + (((uint32_t)s1 << 8) + fo), t1);
            #pragma unroll
            for (int i = 0; i < F; ++i) {
                a0[i] += t0[i];
                a1[i] += t1[i];
            }
        }
        if (g < nf) {
            int s0 = __shfl(cidx, 4 * g + q);
            float t0[F];
            frag_load<F, NOL1>(tSb + (((uint32_t)s0 << 8) + fo), t0);
            #pragma unroll
            for (int i = 0; i < F; ++i) a0[i] += t0[i];
        }
        int tail = m & 3;
        if (tail) {
            int s = __shfl(cidx, 4 * nf + q);   // all lanes active here
            if (q < tail) {
                float t[F];
                frag_load<F, NOL1>(tSb + (((uint32_t)s << 8) + fo), t);
                #pragma unroll
                for (int i = 0; i < F; ++i) a0[i] += t[i];
            }
        }
    }
    #pragma unroll
    for (int i = 0; i < F; ++i) {
        float t = a0[i] + a1[i];
        t += __shfl_xor(t, 16);
        t += __shfl_xor(t, 32);
        acc[i] = t;
    }
}

// gather layer 1, HALF pass (F=4): out feats [hoff, hoff+64) =
// relu(dinv[n]*(tS[n] + sum in-edges) + b). Launched twice (hoff=0,64).
__global__ __launch_bounds__(256) void k_gather1(const _Float16* __restrict__ tS,
                                                 const int* __restrict__ rowptr,
                                                 const int* __restrict__ col,
                                                 const float* __restrict__ dinv,
                                                 const float* __restrict__ b,
                                                 _Float16* __restrict__ out,
                                                 int n, int hoff) {
    int node = blockIdx.x * 4 + (threadIdx.x >> 6);
    int lane = threadIdx.x & 63;
    int q = lane >> 4, l16 = lane & 15;
    if (node >= n) return;
    int e0 = rowptr[node], end = rowptr[node + 1];
    const int hoffB = hoff * 2;
    float acc[4];
    gather_rows_f<4, false>(tS, col, node, e0, end, hoffB, acc);
    if (q == 0) {
        float dn = dinv[node];
        float4 bb = ((const float4*)b)[(hoff >> 2) + l16];
        half4v hv;
        hv[0] = (_Float16)fmaxf(dn * acc[0] + bb.x, 0.0f);
        hv[1] = (_Float16)fmaxf(dn * acc[1] + bb.y, 0.0f);
        hv[2] = (_Float16)fmaxf(dn * acc[2] + bb.z, 0.0f);
        hv[3] = (_Float16)fmaxf(dn * acc[3] + bb.w, 0.0f);
        *(half4v*)((char*)out + (((size_t)node << 8) + hoffB + l16 * 8)) = hv;
    }
}

// gather layer 2, QUARTER pass (F=2), fused with pool head: partial dot over
// feats [hoff, hoff+32) atomically added to pool[batch[n]]. Launched 4x.
__global__ __launch_bounds__(256) void k_gather2(const _Float16* __restrict__ tS,
                                                 const int* __restrict__ rowptr,
                                                 const int* __restrict__ col,
                                                 const float* __restrict__ dinv,
                                                 const float* __restrict__ b,
                                                 const float* __restrict__ Wp,
                                                 const int* __restrict__ batch,
                                                 float* __restrict__ pool,
                                                 int n, int hoff) {
    int node = blockIdx.x * 4 + (threadIdx.x >> 6);
    int lane = threadIdx.x & 63;
    int l16 = lane & 15;
    if (node >= n) return;
    int e0 = rowptr[node], end = rowptr[node + 1];
    const int hoffB = hoff * 2;
    float acc[2];
    gather_rows_f<2, true>(tS, col, node, e0, end, hoffB, acc);
    float dn = dinv[node];
    float2 bb = ((const float2*)b)[(hoff >> 1) + l16];
    float2 wp = ((const float2*)Wp)[(hoff >> 1) + l16];
    float s = fmaxf(dn * acc[0] + bb.x, 0.0f) * wp.x +
              fmaxf(dn * acc[1] + bb.y, 0.0f) * wp.y;
    s += __shfl_xor(s, 1);
    s += __shfl_xor(s, 2);
    s += __shfl_xor(s, 4);
    s += __shfl_xor(s, 8);
    if (lane == 0) {
        int g = batch[node];
        atomicAdd(&pool[g], s);
    }
}

// ---------------------------------------------------------------------------
// batch is sorted: per-graph node counts via binary search (replaces 100K
// float atomics previously done in gather2).
__global__ __launch_bounds__(256) void final_out_kernel(const float* __restrict__ pool,
                                                        const int* __restrict__ batch,
                                                        const float* __restrict__ bp,
                                                        float* __restrict__ out, int g) {
    int i = blockIdx.x * 256 + threadIdx.x;
    if (i >= g) return;
    int lo = 0, hi = NN;
    while (lo < hi) { int mid = (lo + hi) >> 1; if (batch[mid] < i) lo = mid + 1; else hi = mid; }
    int s0 = lo;
    hi = NN;
    while (lo < hi) { int mid = (lo + hi) >> 1; if (batch[mid] < i + 1) lo = mid + 1; else hi = mid; }
    float c = (float)(lo - s0);
    out[i] = pool[i] / fmaxf(c, 1.0f) + bp[0];
}

// ---------------------------------------------------------------------------
extern "C" void kernel_launch(void* const* d_in, const int* in_sizes, int n_in,
                              void* d_out, int out_size, void* d_ws, size_t ws_size,
                              hipStream_t stream) {
    const float* x     = (const float*)d_in[0];
    const int*   ei    = (const int*)d_in[1];   // [2, E]: src = ei[0:E], dst = ei[E:2E]
    const int*   batch = (const int*)d_in[2];
    const float* W1    = (const float*)d_in[3];
    const float* b1    = (const float*)d_in[4];
    const float* W2    = (const float*)d_in[5];
    const float* b2    = (const float*)d_in[6];
    const float* Wp    = (const float*)d_in[7];
    const float* bp    = (const float*)d_in[8];
    float* out = (float*)d_out;

    const int E = in_sizes[1] / 2;   // 1,600,000
    const int* src = ei;
    const int* dst = ei + E;

    // workspace layout
    const size_t BUFH = (size_t)NN * H * sizeof(_Float16);   // 25.6 MB
    const size_t NI   = 401408;                               // >= (NN+1)*4, 4KB-mult
    char* ws = (char*)d_ws;
    size_t off = 0;
    _Float16* tS   = (_Float16*)(ws + off); off += BUFH;     // GEMM1 out (fp16)
    _Float16* h1   = (_Float16*)(ws + off); off += BUFH;     // layer-1 acts (fp16)
    _Float16* tS2  = (_Float16*)(ws + off); off += BUFH;     // GEMM2 out (fp16)
    int*      deg  = (int*)     (ws + off); off += NI;
    int*   rowptr  = (int*)     (ws + off); off += NI;
    int*   cursor  = (int*)     (ws + off); off += NI;
    float*    dinv = (float*)   (ws + off); off += NI;
    int*      col  = (int*)     (ws + off); off += ((size_t)E * 4 + 4095) / 4096 * 4096;
    _Float16* Wt1  = (_Float16*)(ws + off); off += 32768;
    _Float16* Wt2  = (_Float16*)(ws + off); off += 32768;
    int*      bsum = (int*)     (ws + off); off += 4096;
    float*    pool = (float*)   (ws + off); off += 2048;

    const int NB  = (NN + 255) / 256;   // 391 scan blocks
    const int NFB = (E + 255) / 256;    // 6250 fill/hist blocks
    const int NGB = (NN + 63) / 64;     // 1563 gemm blocks
    const int NGA = (NN + 3) / 4;       // 25000 gather blocks (4 nodes/block)

    // --- weights prep ∥ histogram (one dispatch), then scans ---
    hipMemsetAsync(deg, 0, NN * sizeof(int), stream);
    hipMemsetAsync(pool, 0, 2048, stream);
    k_wprep_hist<<<128 + NFB, 256, 0, stream>>>(W1, W2, Wt1, Wt2, dst, deg, E);
    k_scan_block<<<NB, 256, 0, stream>>>(deg, rowptr, bsum, NN);
    k_scan_top<<<1, 512, 0, stream>>>(bsum, NB);
    k_scan_fin<<<NB, 256, 0, stream>>>(rowptr, bsum, deg, cursor, dinv, NN, E);

    // --- fill CSR  ∥  GEMM1 (one dispatch, disjoint block ranges) ---
    k_fill_gemm1<<<NFB + NGB, 256, 0, stream>>>(src, dst, cursor, col, E, NFB,
                                                x, Wt1, dinv, tS, NN);

    // --- layer 1: gather in two HALF-feature passes (12.8MB footprint each),
    //     then LDS-free MFMA GEMM2 ---
    k_gather1<<<NGA, 256, 0, stream>>>(tS, rowptr, col, dinv, b1, h1, NN, 0);
    k_gather1<<<NGA, 256, 0, stream>>>(tS, rowptr, col, dinv, b1, h1, NN, 64);
    k_gemm2<<<NGB, 256, 0, stream>>>(h1, Wt2, dinv, tS2, NN);

    // --- layer 2: gather+pool in four QUARTER-feature passes (6.4MB each) ---
    k_gather2<<<NGA, 256, 0, stream>>>(tS2, rowptr, col, dinv, b2, Wp, batch, pool, NN, 0);
    k_gather2<<<NGA, 256, 0, stream>>>(tS2, rowptr, col, dinv, b2, Wp, batch, pool, NN, 32);
    k_gather2<<<NGA, 256, 0, stream>>>(tS2, rowptr, col, dinv, b2, Wp, batch, pool, NN, 64);
    k_gather2<<<NGA, 256, 0, stream>>>(tS2, rowptr, col, dinv, b2, Wp, batch, pool, NN, 96);

    // --- head ---
    final_out_kernel<<<(NG + 255) / 256, 256, 0, stream>>>(pool, batch, bp, out, NG);
}

// Round 4
// 692.391 us; speedup vs baseline: 2.2094x; 2.2094x over previous
//
#include <hip/hip_runtime.h>
#include <hip/hip_bf16.h>

// Problem constants (match reference)
#define NN 100000
#define NG 512
#define H  128

typedef _Float16 half8 __attribute__((ext_vector_type(8)));
typedef float f32x4 __attribute__((ext_vector_type(4)));

// ---------------------------------------------------------------------------
// Merged: blocks [0,128) transpose+fp16-convert W1/W2; blocks [128,..) dst hist
__global__ __launch_bounds__(256) void k_wprep_hist(const float* __restrict__ W1,
                                                    const float* __restrict__ W2,
                                                    _Float16* __restrict__ Wt1,
                                                    _Float16* __restrict__ Wt2,
                                                    const int* __restrict__ dst,
                                                    int* __restrict__ deg, int E) {
    int bb = blockIdx.x;
    if (bb < 128) {
        const float* W = (bb < 64) ? W1 : W2;
        _Float16* Wt = (bb < 64) ? Wt1 : Wt2;
        int i = (bb & 63) * 256 + threadIdx.x;    // 0..16383
        int k = i >> 7, n = i & 127;
        Wt[n * 128 + k] = (_Float16)W[i];
        return;
    }
    int e = (bb - 128) * 256 + threadIdx.x;
    if (e < E) atomicAdd(&deg[dst[e]], 1);
}

// per-block exclusive scan (256 elems), partial sums to bsum
__global__ __launch_bounds__(256) void k_scan_block(const int* __restrict__ deg,
                                                    int* __restrict__ rowptr,
                                                    int* __restrict__ bsum, int n) {
    __shared__ int s[256];
    int tid = threadIdx.x;
    int i = blockIdx.x * 256 + tid;
    int v = (i < n) ? deg[i] : 0;
    s[tid] = v;
    __syncthreads();
    #pragma unroll
    for (int off = 1; off < 256; off <<= 1) {
        int t = (tid >= off) ? s[tid - off] : 0;
        __syncthreads();
        s[tid] += t;
        __syncthreads();
    }
    if (i < n) rowptr[i] = s[tid] - v;            // exclusive within block
    if (tid == 255) bsum[blockIdx.x] = s[255];    // block total
}

// scan of block sums (nb <= 512), single block
__global__ __launch_bounds__(512) void k_scan_top(int* __restrict__ bsum, int nb) {
    __shared__ int s[512];
    int tid = threadIdx.x;
    int v = (tid < nb) ? bsum[tid] : 0;
    s[tid] = v;
    __syncthreads();
    #pragma unroll
    for (int off = 1; off < 512; off <<= 1) {
        int t = (tid >= off) ? s[tid - off] : 0;
        __syncthreads();
        s[tid] += t;
        __syncthreads();
    }
    if (tid < nb) bsum[tid] = s[tid] - v;         // exclusive
}

// finalize: rowptr += block offset; cursor = rowptr; dinv = rsqrt(deg+1)
__global__ __launch_bounds__(256) void k_scan_fin(int* __restrict__ rowptr,
                                                  const int* __restrict__ bsum,
                                                  const int* __restrict__ deg,
                                                  int* __restrict__ cursor,
                                                  float* __restrict__ dinv,
                                                  int n, int E) {
    int i = blockIdx.x * 256 + threadIdx.x;
    if (i >= n) return;
    int r = rowptr[i] + bsum[i >> 8];
    rowptr[i] = r;
    cursor[i] = r;
    dinv[i] = rsqrtf((float)deg[i] + 1.0f);       // +1 self-loop; always > 0
    if (i == 0) rowptr[n] = E;
}

// ---------------------------------------------------------------------------
// Fused: blocks [0,nfb) fill CSR col; blocks [nfb,..) do GEMM1
// (tS = (x@W1)*dinv[row], fp16 out). LDS-free MFMA GEMM.
__global__ __launch_bounds__(256) void k_fill_gemm1(
        const int* __restrict__ src, const int* __restrict__ dst,
        int* __restrict__ cursor, int* __restrict__ col, int E, int nfb,
        const float* __restrict__ x, const _Float16* __restrict__ Wt1,
        const float* __restrict__ dinv, _Float16* __restrict__ tS, int n) {
    if ((int)blockIdx.x < nfb) {
        int e = blockIdx.x * 256 + threadIdx.x;
        if (e >= E) return;
        int d = dst[e];
        int pos = atomicAdd(&cursor[d], 1);
        col[pos] = src[e];
        return;
    }
    const int row0 = ((int)blockIdx.x - nfb) * 64;
    const int tid = threadIdx.x;
    const int w = tid >> 6, lane = tid & 63;
    const int l16 = lane & 15, quad = lane >> 4;
    const int Arow = row0 + w * 16 + l16;
    f32x4 acc[8] = {};
    #pragma unroll
    for (int kk = 0; kk < 4; ++kk) {
        half8 af;
        if (Arow < n) {
            const float* ap = x + (size_t)Arow * H + kk * 32 + quad * 8;
            float4 a0 = ((const float4*)ap)[0];
            float4 a1 = ((const float4*)ap)[1];
            af[0] = (_Float16)a0.x; af[1] = (_Float16)a0.y;
            af[2] = (_Float16)a0.z; af[3] = (_Float16)a0.w;
            af[4] = (_Float16)a1.x; af[5] = (_Float16)a1.y;
            af[6] = (_Float16)a1.z; af[7] = (_Float16)a1.w;
        } else {
            #pragma unroll
            for (int j = 0; j < 8; ++j) af[j] = (_Float16)0.0f;
        }
        #pragma unroll
        for (int nt = 0; nt < 8; ++nt) {
            half8 bf = *((const half8*)(Wt1 + (nt * 16 + l16) * H + kk * 32 + quad * 8));
            acc[nt] = __builtin_amdgcn_mfma_f32_16x16x32_f16(af, bf, acc[nt], 0, 0, 0);
        }
    }
    #pragma unroll
    for (int r = 0; r < 4; ++r) {
        int R = row0 + w * 16 + quad * 4 + r;
        if (R < n) {
            float sc = dinv[R];
            _Float16* crow = tS + (size_t)R * H + l16;
            #pragma unroll
            for (int nt = 0; nt < 8; ++nt)
                crow[nt * 16] = (_Float16)(acc[nt][r] * sc);
        }
    }
}

// ---------------------------------------------------------------------------
// GEMM2, LDS-free: tS2 = (h1 @ W2) * dinv[row]
__global__ __launch_bounds__(256) void k_gemm2(const _Float16* __restrict__ h1,
                                               const _Float16* __restrict__ Wt2,
                                               const float* __restrict__ dinv,
                                               _Float16* __restrict__ tS2, int n) {
    const int row0 = blockIdx.x * 64;
    const int tid = threadIdx.x;
    const int w = tid >> 6, lane = tid & 63;
    const int l16 = lane & 15, quad = lane >> 4;
    const int Arow = row0 + w * 16 + l16;
    f32x4 acc[8] = {};
    #pragma unroll
    for (int kk = 0; kk < 4; ++kk) {
        half8 af;
        if (Arow < n) {
            af = ((const half8*)(h1 + (size_t)Arow * H))[kk * 4 + quad];
        } else {
            #pragma unroll
            for (int j = 0; j < 8; ++j) af[j] = (_Float16)0.0f;
        }
        #pragma unroll
        for (int nt = 0; nt < 8; ++nt) {
            half8 bf = *((const half8*)(Wt2 + (nt * 16 + l16) * H + kk * 32 + quad * 8));
            acc[nt] = __builtin_amdgcn_mfma_f32_16x16x32_f16(af, bf, acc[nt], 0, 0, 0);
        }
    }
    #pragma unroll
    for (int r = 0; r < 4; ++r) {
        int R = row0 + w * 16 + quad * 4 + r;
        if (R < n) {
            float sc = dinv[R];
            _Float16* crow = tS2 + (size_t)R * H + l16;
            #pragma unroll
            for (int nt = 0; nt < 8; ++nt)
                crow[nt * 16] = (_Float16)(acc[nt][r] * sc);
        }
    }
}

// ---------------------------------------------------------------------------
// 16B row-fragment load that BYPASSES L1 (agent-scope relaxed atomic ->
// global_load_dwordx2 sc0). Used ONLY in gather2 (no store stream there;
// measured −4% there, regression in store-heavy gather1).
__device__ __forceinline__ half8 ld_row16_nol1(const _Float16* p) {
    union { unsigned long long u[2]; half8 h; } t;
    const unsigned long long* q = (const unsigned long long*)p;
    t.u[0] = __hip_atomic_load(q,     __ATOMIC_RELAXED, __HIP_MEMORY_SCOPE_AGENT);
    t.u[1] = __hip_atomic_load(q + 1, __ATOMIC_RELAXED, __HIP_MEMORY_SCOPE_AGENT);
    return t.h;
}

// ---------------------------------------------------------------------------
// Gather core, fp16 rows (256B). Quarter-wave q handles edge slot 4g+q; lane
// loads 16B (8 halves) of the row. Inner loop = round-0 proven pattern
// (2 loads in flight, unmasked groups + tail). THE FIRST 64-EDGE col CHUNK IS
// PRELOADED BY THE CALLER (cidx) so that, when a wave processes two
// independent nodes, node B's col fetch is in flight during all of node A's
// body — doubling the wave's independent memory chains (r3 analysis:
// latency x concurrency bound; bytes/misses/depth-in-one-chain all null).
// After xor-16/32 all lanes hold the full sum for feats l16*8..+7.
template <bool NOL1>
__device__ __forceinline__ void gather_core(const _Float16* __restrict__ tS,
                                            const int* __restrict__ col,
                                            int node, int e0, int end, int cidx,
                                            float acc[8]) {
    const int lane = threadIdx.x & 63;
    const int q = lane >> 4;
    const int l16 = lane & 15;
    float a0[8] = {}, a1[8] = {};
    if (q == 0) {                                   // self-loop row (cached load)
        half8 v = ((const half8*)tS)[(size_t)node * 16 + l16];
        #pragma unroll
        for (int i = 0; i < 8; ++i) a0[i] = (float)v[i];
    }
    for (int base = e0; base < end; base += 64) {
        if (base != e0) {                           // chunk 0 preloaded by caller
            int ce = base + lane;
            cidx = (ce < end) ? col[ce] : 0;
        }
        int m = min(64, end - base);
        int nf = m >> 2;                            // full groups of 4 edges
        int g = 0;
        for (; g + 2 <= nf; g += 2) {
            int s0 = __shfl(cidx, 4 * g + q);
            int s1 = __shfl(cidx, 4 * g + 4 + q);
            half8 v0, v1;
            if (NOL1) {
                v0 = ld_row16_nol1(tS + (size_t)s0 * H + l16 * 8);
                v1 = ld_row16_nol1(tS + (size_t)s1 * H + l16 * 8);
            } else {
                v0 = ((const half8*)tS)[(size_t)s0 * 16 + l16];
                v1 = ((const half8*)tS)[(size_t)s1 * 16 + l16];
            }
            #pragma unroll
            for (int i = 0; i < 8; ++i) {
                a0[i] += (float)v0[i];
                a1[i] += (float)v1[i];
            }
        }
        if (g < nf) {
            int s0 = __shfl(cidx, 4 * g + q);
            half8 v0 = NOL1 ? ld_row16_nol1(tS + (size_t)s0 * H + l16 * 8)
                            : ((const half8*)tS)[(size_t)s0 * 16 + l16];
            #pragma unroll
            for (int i = 0; i < 8; ++i) a0[i] += (float)v0[i];
        }
        int tail = m & 3;
        if (tail) {
            int s = __shfl(cidx, 4 * nf + q);       // all lanes active here
            if (q < tail) {
                half8 v = NOL1 ? ld_row16_nol1(tS + (size_t)s * H + l16 * 8)
                               : ((const half8*)tS)[(size_t)s * 16 + l16];
                #pragma unroll
                for (int i = 0; i < 8; ++i) a0[i] += (float)v[i];
            }
        }
    }
    #pragma unroll
    for (int i = 0; i < 8; ++i) {
        float t = a0[i] + a1[i];
        t += __shfl_xor(t, 16);
        t += __shfl_xor(t, 32);
        acc[i] = t;
    }
}

// gather layer 1: out (fp16) = relu(dinv[n]*(tS[n] + sum in-edges) + b).
// 512-thread blocks (8 waves — occupancy lever). One wave handles TWO STRIDED
// nodes (widx, widx+half): independent rowptr/col/row chains, both col chunk-0
// fetches issued before either body.
__global__ __launch_bounds__(512) void k_gather1(const _Float16* __restrict__ tS,
                                                 const int* __restrict__ rowptr,
                                                 const int* __restrict__ col,
                                                 const float* __restrict__ dinv,
                                                 const float* __restrict__ b,
                                                 _Float16* __restrict__ out, int n) {
    int half = (n + 1) >> 1;
    int widx = blockIdx.x * 8 + (threadIdx.x >> 6);
    if (widx >= half) return;
    int nA = widx, nB = widx + half;
    bool hasB = (nB < n);
    int lane = threadIdx.x & 63;
    int q = lane >> 4, l16 = lane & 15;
    int e0A = rowptr[nA], e1A = rowptr[nA + 1];
    int e0B = hasB ? rowptr[nB] : 0;
    int e1B = hasB ? rowptr[nB + 1] : 0;
    int cA = (e0A + lane < e1A) ? col[e0A + lane] : 0;   // chunk 0, node A
    int cB = (e0B + lane < e1B) ? col[e0B + lane] : 0;   // chunk 0, node B (in flight)
    const float4* b4 = (const float4*)b;
    float4 bb0 = b4[2 * l16], bb1 = b4[2 * l16 + 1];
    float acc[8];
    gather_core<false>(tS, col, nA, e0A, e1A, cA, acc);
    if (q == 0) {
        float dn = dinv[nA];
        half8 hv;
        hv[0] = (_Float16)fmaxf(dn * acc[0] + bb0.x, 0.0f);
        hv[1] = (_Float16)fmaxf(dn * acc[1] + bb0.y, 0.0f);
        hv[2] = (_Float16)fmaxf(dn * acc[2] + bb0.z, 0.0f);
        hv[3] = (_Float16)fmaxf(dn * acc[3] + bb0.w, 0.0f);
        hv[4] = (_Float16)fmaxf(dn * acc[4] + bb1.x, 0.0f);
        hv[5] = (_Float16)fmaxf(dn * acc[5] + bb1.y, 0.0f);
        hv[6] = (_Float16)fmaxf(dn * acc[6] + bb1.z, 0.0f);
        hv[7] = (_Float16)fmaxf(dn * acc[7] + bb1.w, 0.0f);
        ((half8*)out)[(size_t)nA * 16 + l16] = hv;
    }
    if (hasB) {
        gather_core<false>(tS, col, nB, e0B, e1B, cB, acc);
        if (q == 0) {
            float dn = dinv[nB];
            half8 hv;
            hv[0] = (_Float16)fmaxf(dn * acc[0] + bb0.x, 0.0f);
            hv[1] = (_Float16)fmaxf(dn * acc[1] + bb0.y, 0.0f);
            hv[2] = (_Float16)fmaxf(dn * acc[2] + bb0.z, 0.0f);
            hv[3] = (_Float16)fmaxf(dn * acc[3] + bb0.w, 0.0f);
            hv[4] = (_Float16)fmaxf(dn * acc[4] + bb1.x, 0.0f);
            hv[5] = (_Float16)fmaxf(dn * acc[5] + bb1.y, 0.0f);
            hv[6] = (_Float16)fmaxf(dn * acc[6] + bb1.z, 0.0f);
            hv[7] = (_Float16)fmaxf(dn * acc[7] + bb1.w, 0.0f);
            ((half8*)out)[(size_t)nB * 16 + l16] = hv;
        }
    }
}

// gather layer 2 fused with pool head: v = relu(...); pool[batch[n]] += dot(v, Wp)
// Same dual-node structure as k_gather1.
__global__ __launch_bounds__(512) void k_gather2(const _Float16* __restrict__ tS,
                                                 const int* __restrict__ rowptr,
                                                 const int* __restrict__ col,
                                                 const float* __restrict__ dinv,
                                                 const float* __restrict__ b,
                                                 const float* __restrict__ Wp,
                                                 const int* __restrict__ batch,
                                                 float* __restrict__ pool, int n) {
    int half = (n + 1) >> 1;
    int widx = blockIdx.x * 8 + (threadIdx.x >> 6);
    if (widx >= half) return;
    int nA = widx, nB = widx + half;
    bool hasB = (nB < n);
    int lane = threadIdx.x & 63;
    int l16 = lane & 15;
    int e0A = rowptr[nA], e1A = rowptr[nA + 1];
    int e0B = hasB ? rowptr[nB] : 0;
    int e1B = hasB ? rowptr[nB + 1] : 0;
    int cA = (e0A + lane < e1A) ? col[e0A + lane] : 0;
    int cB = (e0B + lane < e1B) ? col[e0B + lane] : 0;
    const float4* b4 = (const float4*)b;
    const float4* w4 = (const float4*)Wp;
    float4 bb0 = b4[2 * l16], bb1 = b4[2 * l16 + 1];
    float4 wp0 = w4[2 * l16], wp1 = w4[2 * l16 + 1];
    float acc[8];
    gather_core<true>(tS, col, nA, e0A, e1A, cA, acc);
    {
        float dn = dinv[nA];
        float s = fmaxf(dn * acc[0] + bb0.x, 0.0f) * wp0.x +
                  fmaxf(dn * acc[1] + bb0.y, 0.0f) * wp0.y +
                  fmaxf(dn * acc[2] + bb0.z, 0.0f) * wp0.z +
                  fmaxf(dn * acc[3] + bb0.w, 0.0f) * wp0.w +
                  fmaxf(dn * acc[4] + bb1.x, 0.0f) * wp1.x +
                  fmaxf(dn * acc[5] + bb1.y, 0.0f) * wp1.y +
                  fmaxf(dn * acc[6] + bb1.z, 0.0f) * wp1.z +
                  fmaxf(dn * acc[7] + bb1.w, 0.0f) * wp1.w;
        s += __shfl_xor(s, 1);
        s += __shfl_xor(s, 2);
        s += __shfl_xor(s, 4);
        s += __shfl_xor(s, 8);
        if (lane == 0) atomicAdd(&pool[batch[nA]], s);
    }
    if (hasB) {
        gather_core<true>(tS, col, nB, e0B, e1B, cB, acc);
        float dn = dinv[nB];
        float s = fmaxf(dn * acc[0] + bb0.x, 0.0f) * wp0.x +
                  fmaxf(dn * acc[1] + bb0.y, 0.0f) * wp0.y +
                  fmaxf(dn * acc[2] + bb0.z, 0.0f) * wp0.z +
                  fmaxf(dn * acc[3] + bb0.w, 0.0f) * wp0.w +
                  fmaxf(dn * acc[4] + bb1.x, 0.0f) * wp1.x +
                  fmaxf(dn * acc[5] + bb1.y, 0.0f) * wp1.y +
                  fmaxf(dn * acc[6] + bb1.z, 0.0f) * wp1.z +
                  fmaxf(dn * acc[7] + bb1.w, 0.0f) * wp1.w;
        s += __shfl_xor(s, 1);
        s += __shfl_xor(s, 2);
        s += __shfl_xor(s, 4);
        s += __shfl_xor(s, 8);
        if (lane == 0) atomicAdd(&pool[batch[nB]], s);
    }
}

// ---------------------------------------------------------------------------
// batch is sorted: per-graph node counts via binary search (replaces 100K
// float atomics previously done in gather2).
__global__ __launch_bounds__(256) void final_out_kernel(const float* __restrict__ pool,
                                                        const int* __restrict__ batch,
                                                        const float* __restrict__ bp,
                                                        float* __restrict__ out, int g) {
    int i = blockIdx.x * 256 + threadIdx.x;
    if (i >= g) return;
    int lo = 0, hi = NN;
    while (lo < hi) { int mid = (lo + hi) >> 1; if (batch[mid] < i) lo = mid + 1; else hi = mid; }
    int s0 = lo;
    hi = NN;
    while (lo < hi) { int mid = (lo + hi) >> 1; if (batch[mid] < i + 1) lo = mid + 1; else hi = mid; }
    float c = (float)(lo - s0);
    out[i] = pool[i] / fmaxf(c, 1.0f) + bp[0];
}

// ---------------------------------------------------------------------------
extern "C" void kernel_launch(void* const* d_in, const int* in_sizes, int n_in,
                              void* d_out, int out_size, void* d_ws, size_t ws_size,
                              hipStream_t stream) {
    const float* x     = (const float*)d_in[0];
    const int*   ei    = (const int*)d_in[1];   // [2, E]: src = ei[0:E], dst = ei[E:2E]
    const int*   batch = (const int*)d_in[2];
    const float* W1    = (const float*)d_in[3];
    const float* b1    = (const float*)d_in[4];
    const float* W2    = (const float*)d_in[5];
    const float* b2    = (const float*)d_in[6];
    const float* Wp    = (const float*)d_in[7];
    const float* bp    = (const float*)d_in[8];
    float* out = (float*)d_out;

    const int E = in_sizes[1] / 2;   // 1,600,000
    const int* src = ei;
    const int* dst = ei + E;

    // workspace layout
    const size_t BUFH = (size_t)NN * H * sizeof(_Float16);   // 25.6 MB
    const size_t NI   = 401408;                               // >= (NN+1)*4, 4KB-mult
    char* ws = (char*)d_ws;
    size_t off = 0;
    _Float16* tS   = (_Float16*)(ws + off); off += BUFH;     // GEMM1 out (fp16)
    _Float16* h1   = (_Float16*)(ws + off); off += BUFH;     // layer-1 acts (fp16)
    _Float16* tS2  = (_Float16*)(ws + off); off += BUFH;     // GEMM2 out (fp16)
    int*      deg  = (int*)     (ws + off); off += NI;
    int*   rowptr  = (int*)     (ws + off); off += NI;
    int*   cursor  = (int*)     (ws + off); off += NI;
    float*    dinv = (float*)   (ws + off); off += NI;
    int*      col  = (int*)     (ws + off); off += ((size_t)E * 4 + 4095) / 4096 * 4096;
    _Float16* Wt1  = (_Float16*)(ws + off); off += 32768;
    _Float16* Wt2  = (_Float16*)(ws + off); off += 32768;
    int*      bsum = (int*)     (ws + off); off += 4096;
    float*    pool = (float*)   (ws + off); off += 2048;

    const int NB  = (NN + 255) / 256;   // 391 scan blocks
    const int NFB = (E + 255) / 256;    // 6250 fill/hist blocks
    const int NGB = (NN + 63) / 64;     // 1563 gemm blocks
    const int HALF = (NN + 1) / 2;      // 50000 wave-pairs
    const int NGA = (HALF + 7) / 8;     // 6250 gather blocks (8 waves x 2 nodes)

    // --- weights prep ∥ histogram (one dispatch), then scans ---
    hipMemsetAsync(deg, 0, NN * sizeof(int), stream);
    hipMemsetAsync(pool, 0, 2048, stream);
    k_wprep_hist<<<128 + NFB, 256, 0, stream>>>(W1, W2, Wt1, Wt2, dst, deg, E);
    k_scan_block<<<NB, 256, 0, stream>>>(deg, rowptr, bsum, NN);
    k_scan_top<<<1, 512, 0, stream>>>(bsum, NB);
    k_scan_fin<<<NB, 256, 0, stream>>>(rowptr, bsum, deg, cursor, dinv, NN, E);

    // --- fill CSR  ∥  GEMM1 (one dispatch, disjoint block ranges) ---
    k_fill_gemm1<<<NFB + NGB, 256, 0, stream>>>(src, dst, cursor, col, E, NFB,
                                                x, Wt1, dinv, tS, NN);

    // --- layer 1: dual-node gather then LDS-free MFMA GEMM2 ---
    k_gather1<<<NGA, 512, 0, stream>>>(tS, rowptr, col, dinv, b1, h1, NN);
    k_gemm2<<<NGB, 256, 0, stream>>>(h1, Wt2, dinv, tS2, NN);

    // --- layer 2 dual-node gather + pool head ---
    k_gather2<<<NGA, 512, 0, stream>>>(tS2, rowptr, col, dinv, b2, Wp,
                                       batch, pool, NN);

    // --- head ---
    final_out_kernel<<<(NG + 255) / 256, 256, 0, stream>>>(pool, batch, bp, out, NG);
}